// Round 3
// baseline (418.305 us; speedup 1.0000x reference)
//
#include <hip/hip_runtime.h>
#include <hip/hip_bf16.h>
#include <stdint.h>

// HGNN layer: out = dv*(H*(de*(H^T*(dv*x))))*W^T + b
// N=20000, E=4096, D=128, f32 inputs.
// R3: k_pre writes HbT=bf16(H)^T so gemm1 is pure global_load_lds (both ops);
// BK=64 single-barrier dbuf pipelines; colsum via ones-MFMA; cvt_pk staging.

#define N_ 20000
#define E_ 4096
#define D_ 128
#define HBT_S 20032   // HbT row stride (zero-padded tail)

typedef __attribute__((ext_vector_type(8))) short    bf16x8;
typedef __attribute__((ext_vector_type(4))) float    f32x4;
typedef __attribute__((ext_vector_type(8))) unsigned short us8;
typedef __attribute__((ext_vector_type(4))) unsigned short us4;

__device__ __forceinline__ unsigned short f2bf(float f) {
  unsigned u = __float_as_uint(f);
  u += 0x7FFFu + ((u >> 16) & 1u);        // RNE
  return (unsigned short)(u >> 16);
}
__device__ __forceinline__ unsigned cvtpk(float lo, float hi) {
  unsigned r;
  asm("v_cvt_pk_bf16_f32 %0, %1, %2" : "=v"(r) : "v"(lo), "v"(hi));
  return r;
}
__device__ __forceinline__ void gload16(const unsigned short* g, unsigned short* l) {
  __builtin_amdgcn_global_load_lds(
      (const __attribute__((address_space(1))) unsigned int*)g,
      (__attribute__((address_space(3))) unsigned int*)l, 16, 0, 0);
}

// ---------------------------------------------------------------------------
// k_pre: rowsum -> dv; HbT[e][n] = bf16(H[n][e]); xTb[d][n] = bf16(dv*x).
// 2504 blocks x 256 (blocks 2500+ zero HbT's pad cols 20000..20031).
// ---------------------------------------------------------------------------
__global__ __launch_bounds__(256) void k_pre(const float* __restrict__ H,
                                             const float* __restrict__ x,
                                             float* __restrict__ dv,
                                             unsigned short* __restrict__ HbT,
                                             unsigned short* __restrict__ xTb) {
  const int t = threadIdx.x, lane = t & 63, w = t >> 6;
  const int b = blockIdx.x;
  const int n0 = b * 8;
  if (b >= 2500) {                        // zero the HbT pad columns
    for (int e = t; e < E_; e += 256)
      *(us8*)(HbT + (size_t)e * HBT_S + n0) = (us8){0,0,0,0,0,0,0,0};
    return;
  }
  __shared__ float red[32];
  __shared__ float xt[8 * 128];
  {                                       // x tile [8 n][128 d]
    int r = t >> 5, d4 = (t & 31) * 4;
    *(f32x4*)&xt[r * 128 + d4] = *(const f32x4*)(x + (size_t)(n0 + r) * D_ + d4);
  }
  float rs[8];
#pragma unroll
  for (int r = 0; r < 8; ++r) rs[r] = 0.f;
#pragma unroll
  for (int j = 0; j < 4; ++j) {           // col-group: cols j*1024 + t*4 + c
    float f[4][8];
#pragma unroll
    for (int r = 0; r < 8; ++r) {
      f32x4 v = *(const f32x4*)(H + (size_t)(n0 + r) * E_ + j * 1024 + t * 4);
      f[0][r] = v.x; f[1][r] = v.y; f[2][r] = v.z; f[3][r] = v.w;
      rs[r] += (v.x + v.y) + (v.z + v.w);
    }
#pragma unroll
    for (int c = 0; c < 4; ++c) {
      union { us8 v8; unsigned u32[4]; } un;
#pragma unroll
      for (int p = 0; p < 4; ++p) un.u32[p] = cvtpk(f[c][2 * p], f[c][2 * p + 1]);
      *(us8*)(HbT + (size_t)(j * 1024 + t * 4 + c) * HBT_S + n0) = un.v8;
    }
  }
#pragma unroll
  for (int r = 0; r < 8; ++r)
#pragma unroll
    for (int off = 32; off; off >>= 1) rs[r] += __shfl_xor(rs[r], off);
  if (lane == 0) {
#pragma unroll
    for (int r = 0; r < 8; ++r) red[w * 8 + r] = rs[r];
  }
  __syncthreads();
  if (t < 8) {
    float s = red[t] + red[8 + t] + red[16 + t] + red[24 + t];
    float d = s > 0.f ? rsqrtf(s) : 0.f;
    dv[n0 + t] = d;
    red[t] = d;                           // broadcast cache (disjoint r/w, see R2)
  }
  __syncthreads();
  if (t < 128) {                          // xTb[d][n0..n0+8)
    int d = t;
    float v[8];
#pragma unroll
    for (int r = 0; r < 8; ++r) v[r] = xt[r * 128 + d] * red[r];
    union { us8 v8; unsigned u32[4]; } un;
#pragma unroll
    for (int j = 0; j < 4; ++j) un.u32[j] = cvtpk(v[2 * j], v[2 * j + 1]);
    *(us8*)(xTb + (size_t)d * N_ + n0) = un.v8;
  }
}

// de[e] = colsum>0 ? 1/colsum : 0  (after gemm1)
__global__ __launch_bounds__(256) void k_fin(const float* __restrict__ desum,
                                             float* __restrict__ de) {
  int e = blockIdx.x * 256 + threadIdx.x;
  float s = desum[e];
  de[e] = s > 0.f ? 1.f / s : 0.f;
}

// Wb = bf16(W), [j][d]
__global__ __launch_bounds__(256) void k_wb(const float* __restrict__ W,
                                            unsigned short* __restrict__ Wb) {
  int tid = blockIdx.x * 256 + threadIdx.x;
  float4 v = *(const float4*)(W + (size_t)tid * 4);
  union { us4 v; unsigned short u[4]; } un;
  un.u[0] = f2bf(v.x); un.u[1] = f2bf(v.y); un.u[2] = f2bf(v.z); un.u[3] = f2bf(v.w);
  *(us4*)(Wb + (size_t)tid * 4) = un.v;
}

// ---------------------------------------------------------------------------
// GEMM1: partialT[s][d][e] = sum_{n chunk s} HbT[e][n] * xTb[d][n]
// 64e x 128d block, BK=64, dbuf, both operands via pre-swizzled gload16.
// Colsum (desum) via ones-MFMA on already-loaded A frags (waves wx==0).
// grid = 64 e-blocks * 8 chunks; chunk = 39 steps (+1 tail for s=7).
// ---------------------------------------------------------------------------
__global__ __launch_bounds__(256) void k_gemm1(const unsigned short* __restrict__ HbT,
                                               const unsigned short* __restrict__ xTb,
                                               float* __restrict__ partialT,
                                               float* __restrict__ desum) {
  __shared__ unsigned short lA[2][64 * 64];   // [e][64n], XOR-swizzled content
  __shared__ unsigned short lB[2][128 * 64];  // [d][64n], XOR-swizzled content
  const int t = threadIdx.x, lane = t & 63, w = t >> 6;
  const int eb = blockIdx.x & 63, s = blockIdx.x >> 6;
  const int e0 = eb * 64;
  const int nsteps = 39 + (s == 7);
  const int g0 = s * 39;
  const int lrow = lane >> 3, lslot = lane & 7;
  const int bswz = (lslot ^ lrow) << 3;       // pre-swizzled source offset
  const int wy = w >> 1, wx = w & 1;

  f32x4 acc[2][4];
  f32x4 accC[2];
#pragma unroll
  for (int i = 0; i < 2; ++i) {
    accC[i] = (f32x4){0.f, 0.f, 0.f, 0.f};
#pragma unroll
    for (int j = 0; j < 4; ++j) acc[i][j] = (f32x4){0.f, 0.f, 0.f, 0.f};
  }
  bf16x8 ones;
#pragma unroll
  for (int q = 0; q < 8; ++q) ones[q] = (short)0x3F80;

  auto STAGE = [&](int g, int bufi) {
    const int n0 = g * 64;
#pragma unroll
    for (int i = 0; i < 2; ++i) {             // A: 2 chunks/wave (8KB total)
      int c = w * 2 + i;
      gload16(HbT + (size_t)(e0 + 8 * c + lrow) * HBT_S + n0 + bswz,
              &lA[bufi][c * 512]);
    }
#pragma unroll
    for (int i = 0; i < 4; ++i) {             // B: 4 chunks/wave (16KB total)
      int c = w * 4 + i;
      gload16(xTb + (size_t)(8 * c + lrow) * N_ + n0 + bswz,
              &lB[bufi][c * 512]);
    }
  };

  STAGE(g0, 0);
  __syncthreads();
  int cur = 0;
  for (int it = 0; it < nsteps; ++it) {
    if (it + 1 < nsteps) STAGE(g0 + it + 1, cur ^ 1);
    const int kg = lane >> 4, fr = lane & 15;
    bf16x8 af[2][2], bfr[4][2];
#pragma unroll
    for (int mi = 0; mi < 2; ++mi) {
      int m = wy * 32 + mi * 16 + fr;
#pragma unroll
      for (int kk = 0; kk < 2; ++kk)
        af[mi][kk] = *(const bf16x8*)&lA[cur][m * 64 + (((kk * 4 + kg) ^ (m & 7)) << 3)];
    }
#pragma unroll
    for (int ni = 0; ni < 4; ++ni) {
      int d = wx * 64 + ni * 16 + fr;
#pragma unroll
      for (int kk = 0; kk < 2; ++kk)
        bfr[ni][kk] = *(const bf16x8*)&lB[cur][d * 64 + (((kk * 4 + kg) ^ (d & 7)) << 3)];
    }
#pragma unroll
    for (int kk = 0; kk < 2; ++kk)
#pragma unroll
      for (int mi = 0; mi < 2; ++mi)
#pragma unroll
        for (int ni = 0; ni < 4; ++ni)
          acc[mi][ni] = __builtin_amdgcn_mfma_f32_16x16x32_bf16(af[mi][kk], bfr[ni][kk], acc[mi][ni], 0, 0, 0);
    if (wx == 0) {                            // colsum rows: D[m][*] = sum_k A[m][k]
#pragma unroll
      for (int kk = 0; kk < 2; ++kk)
#pragma unroll
        for (int mi = 0; mi < 2; ++mi)
          accC[mi] = __builtin_amdgcn_mfma_f32_16x16x32_bf16(af[mi][kk], ones, accC[mi], 0, 0, 0);
    }
    __syncthreads();
    cur ^= 1;
  }
  // colsum flush: 64 atomics/block
  if (wx == 0 && (lane & 15) == 0) {
#pragma unroll
    for (int mi = 0; mi < 2; ++mi)
#pragma unroll
      for (int r = 0; r < 4; ++r) {
        int e = e0 + wy * 32 + mi * 16 + (lane >> 4) * 4 + r;
        atomicAdd(&desum[e], accC[mi][r]);
      }
  }
  // partialT[s][d][e]
#pragma unroll
  for (int mi = 0; mi < 2; ++mi)
#pragma unroll
    for (int ni = 0; ni < 4; ++ni)
#pragma unroll
      for (int r = 0; r < 4; ++r) {
        int e = e0 + wy * 32 + mi * 16 + (lane >> 4) * 4 + r;
        int d = wx * 64 + ni * 16 + (lane & 15);
        partialT[((size_t)s * 128 + d) * E_ + e] = acc[mi][ni][r];
      }
}

// x3T[d][e] = bf16(de[e] * sum_s partialT[s][d][e])
__global__ __launch_bounds__(256) void k_reduce1(const float* __restrict__ partialT,
                                                 const float* __restrict__ de,
                                                 unsigned short* __restrict__ x3T) {
  int tid = blockIdx.x * 256 + threadIdx.x;
  int d = tid >> 12, e = tid & 4095;
  float s = 0.f;
#pragma unroll
  for (int ss = 0; ss < 8; ++ss) s += partialT[((size_t)ss * 128 + d) * E_ + e];
  x3T[(size_t)d * E_ + e] = f2bf(de[e] * s);
}

// ---------------------------------------------------------------------------
// GEMM2: out = (dv*(H @ x3)) @ W^T + b.  64n x 128d block, BK=64, dbuf.
// A: reg-staged f32 H + cvt_pk + swizzled ds_write; B: pre-swizzled gload.
// Epilogue: dv-scale -> bf16 lC (stride 136) -> W MFMA -> +bias.
// ---------------------------------------------------------------------------
__global__ __launch_bounds__(256) void k_gemm2(const float* __restrict__ H,
                                               const unsigned short* __restrict__ x3T,
                                               const unsigned short* __restrict__ Wb,
                                               const float* __restrict__ dv,
                                               const float* __restrict__ bias,
                                               float* __restrict__ out) {
  __shared__ unsigned short sm[2 * 64 * 64 + 2 * 128 * 64];  // lA dbuf | lB dbuf
  __shared__ unsigned short lW[128 * 128];
  unsigned short (*lA)[64 * 64]  = (unsigned short (*)[64 * 64])sm;
  unsigned short (*lB)[128 * 64] = (unsigned short (*)[128 * 64])(sm + 2 * 64 * 64);
  unsigned short* lC = sm;                    // 64*136 = 8704 shorts, aliases stage
  const int t = threadIdx.x, lane = t & 63, w = t >> 6;
  const int n0b = blockIdx.x * 64;
  const int lrow = lane >> 3, lslot = lane & 7;
  const int bswz = (lslot ^ lrow) << 3;
  const int wy = w >> 1, wx = w & 1;

  // A staging map: thread -> row an, slots kb0 / kb0^4 (2-way-free write swizzle)
  const int an  = t >> 2;
  const int kb0 = (t & 3) + 4 * (an & 1);
  const int kb1 = kb0 ^ 4;
  const float* arow = H + (size_t)min(n0b + an, N_ - 1) * E_;
  float ar[2][8];

  {                                           // stage W [j][d] once
    int j = t >> 1;
#pragma unroll
    for (int jj = 0; jj < 4; ++jj) {
      int dofs = (t & 1) * 64 + jj * 16;
      const us8* src = (const us8*)(Wb + (size_t)j * 128 + dofs);
      *(us8*)&lW[j * 128 + dofs]     = src[0];
      *(us8*)&lW[j * 128 + dofs + 8] = src[1];
    }
  }

  auto LOADA = [&](int g) {
    const float* p = arow + g * 64;
    f32x4 u0 = *(const f32x4*)(p + kb0 * 8);
    f32x4 u1 = *(const f32x4*)(p + kb0 * 8 + 4);
    ar[0][0] = u0.x; ar[0][1] = u0.y; ar[0][2] = u0.z; ar[0][3] = u0.w;
    ar[0][4] = u1.x; ar[0][5] = u1.y; ar[0][6] = u1.z; ar[0][7] = u1.w;
    f32x4 u2 = *(const f32x4*)(p + kb1 * 8);
    f32x4 u3 = *(const f32x4*)(p + kb1 * 8 + 4);
    ar[1][0] = u2.x; ar[1][1] = u2.y; ar[1][2] = u2.z; ar[1][3] = u2.w;
    ar[1][4] = u3.x; ar[1][5] = u3.y; ar[1][6] = u3.z; ar[1][7] = u3.w;
  };
  auto WRITEA = [&](int bufi) {
#pragma unroll
    for (int q = 0; q < 2; ++q) {
      int kb = q ? kb1 : kb0;
      union { bf16x8 v; unsigned u32[4]; } un;
#pragma unroll
      for (int j = 0; j < 4; ++j) un.u32[j] = cvtpk(ar[q][2 * j], ar[q][2 * j + 1]);
      *(bf16x8*)&lA[bufi][an * 64 + ((kb ^ (an & 7)) << 3)] = un.v;
    }
  };
  auto GLOADB = [&](int g, int bufi) {
#pragma unroll
    for (int i = 0; i < 4; ++i) {
      int c = w * 4 + i;
      gload16(x3T + (size_t)(8 * c + lrow) * E_ + g * 64 + bswz,
              &lB[bufi][c * 512]);
    }
  };

  f32x4 acc[2][4];
#pragma unroll
  for (int i = 0; i < 2; ++i)
#pragma unroll
    for (int j = 0; j < 4; ++j) acc[i][j] = (f32x4){0.f, 0.f, 0.f, 0.f};

  LOADA(0); WRITEA(0); GLOADB(0, 0);
  __syncthreads();
  int cur = 0;
  for (int it = 0; it < 64; ++it) {
    bool hn = it < 63;
    if (hn) { LOADA(it + 1); GLOADB(it + 1, cur ^ 1); }
    const int kg = lane >> 4, fr = lane & 15;
    bf16x8 af[2][2], bfr[4][2];
#pragma unroll
    for (int mi = 0; mi < 2; ++mi) {
      int m = wy * 32 + mi * 16 + fr;
#pragma unroll
      for (int kk = 0; kk < 2; ++kk)
        af[mi][kk] = *(const bf16x8*)&lA[cur][m * 64 + (((kk * 4 + kg) ^ (m & 7)) << 3)];
    }
#pragma unroll
    for (int ni = 0; ni < 4; ++ni) {
      int d = wx * 64 + ni * 16 + fr;
#pragma unroll
      for (int kk = 0; kk < 2; ++kk)
        bfr[ni][kk] = *(const bf16x8*)&lB[cur][d * 64 + (((kk * 4 + kg) ^ (d & 7)) << 3)];
    }
#pragma unroll
    for (int kk = 0; kk < 2; ++kk)
#pragma unroll
      for (int mi = 0; mi < 2; ++mi)
#pragma unroll
        for (int ni = 0; ni < 4; ++ni)
          acc[mi][ni] = __builtin_amdgcn_mfma_f32_16x16x32_bf16(af[mi][kk], bfr[ni][kk], acc[mi][ni], 0, 0, 0);
    if (hn) WRITEA(cur ^ 1);
    __syncthreads();
    cur ^= 1;
  }
  // epilogue: dv-scale -> bf16 -> lC (stride 136)
#pragma unroll
  for (int mi = 0; mi < 2; ++mi) {
    float dvv[4];
#pragma unroll
    for (int r = 0; r < 4; ++r)
      dvv[r] = dv[min(n0b + wy * 32 + mi * 16 + (lane >> 4) * 4 + r, N_ - 1)];
#pragma unroll
    for (int ni = 0; ni < 4; ++ni)
#pragma unroll
      for (int r = 0; r < 4; ++r) {
        int row = wy * 32 + mi * 16 + (lane >> 4) * 4 + r;
        int col = wx * 64 + ni * 16 + (lane & 15);
        lC[row * 136 + col] = f2bf(acc[mi][ni][r] * dvv[r]);
      }
  }
  __syncthreads();
  f32x4 acc2[2][4];
#pragma unroll
  for (int i = 0; i < 2; ++i)
#pragma unroll
    for (int j = 0; j < 4; ++j) acc2[i][j] = (f32x4){0.f, 0.f, 0.f, 0.f};
#pragma unroll
  for (int ks = 0; ks < 4; ++ks) {
    int kofs = ks * 32 + (lane >> 4) * 8;
    bf16x8 a2[2], b2[4];
#pragma unroll
    for (int mi = 0; mi < 2; ++mi) {
      int m = wy * 32 + mi * 16 + (lane & 15);
      a2[mi] = *(const bf16x8*)&lC[m * 136 + kofs];
    }
#pragma unroll
    for (int ni = 0; ni < 4; ++ni) {
      int j = wx * 64 + ni * 16 + (lane & 15);
      b2[ni] = *(const bf16x8*)&lW[j * 128 + kofs];
    }
#pragma unroll
    for (int mi = 0; mi < 2; ++mi)
#pragma unroll
      for (int ni = 0; ni < 4; ++ni)
        acc2[mi][ni] = __builtin_amdgcn_mfma_f32_16x16x32_bf16(a2[mi], b2[ni], acc2[mi][ni], 0, 0, 0);
  }
#pragma unroll
  for (int mi = 0; mi < 2; ++mi)
#pragma unroll
    for (int ni = 0; ni < 4; ++ni) {
      int j = wx * 64 + ni * 16 + (lane & 15);
      float bb = bias[j];
#pragma unroll
      for (int r = 0; r < 4; ++r) {
        int n = n0b + wy * 32 + mi * 16 + (lane >> 4) * 4 + r;
        if (n < N_) out[(size_t)n * D_ + j] = acc2[mi][ni][r] + bb;
      }
    }
}

// ---------------------------------------------------------------------------
extern "C" void kernel_launch(void* const* d_in, const int* in_sizes, int n_in,
                              void* d_out, int out_size, void* d_ws, size_t ws_size,
                              hipStream_t stream) {
  const float* x = (const float*)d_in[0];
  const float* H = (const float*)d_in[1];
  const float* W = (const float*)d_in[2];
  const float* b = (const float*)d_in[3];
  float* out = (float*)d_out;
  char* ws = (char*)d_ws;
  float*          desum    = (float*)(ws);                     // 16 KB
  float*          de       = (float*)(ws + 16384);             // 16 KB
  float*          dv       = (float*)(ws + 32768);             // 80 KB pad
  unsigned short* Wb       = (unsigned short*)(ws + 112896);   // 32 KB
  unsigned short* xTb      = (unsigned short*)(ws + 145664);   // 5.12 MB
  unsigned short* x3T      = (unsigned short*)(ws + 5265664);  // 1.05 MB
  float*          partialT = (float*)(ws + 6314240);           // 16.78 MB
  unsigned short* HbT      = (unsigned short*)(ws + 23091456); // 164.1 MB

  hipMemsetAsync(desum, 0, 16384, stream);
  k_pre<<<2504, 256, 0, stream>>>(H, x, dv, HbT, xTb);
  k_wb<<<16, 256, 0, stream>>>(W, Wb);
  k_gemm1<<<512, 256, 0, stream>>>(HbT, xTb, partialT, desum);
  k_fin<<<16, 256, 0, stream>>>(desum, de);
  k_reduce1<<<2048, 256, 0, stream>>>(partialT, de, x3T);
  k_gemm2<<<313, 256, 0, stream>>>(H, x3T, Wb, dv, b, out);
}

// Round 4
// 240.703 us; speedup vs baseline: 1.7378x; 1.7378x over previous
//
#include <hip/hip_runtime.h>
#include <hip/hip_bf16.h>
#include <stdint.h>

// HGNN layer: out = dv*(H*(de*(H^T*(dv*x))))*W^T + b
// N=20000, E=4096, D=128, f32 inputs.
// R4: Hb = bf16(H) same-layout (coalesced write, padded to 20032 rows);
// gemm1 transposes Hb in LDS (swizzled, conflict-free); gemm2 pure gload16.

#define N_ 20000
#define E_ 4096
#define D_ 128
#define NPAD 20032
#define XTB_S 20032

typedef __attribute__((ext_vector_type(8))) short    bf16x8;
typedef __attribute__((ext_vector_type(4))) float    f32x4;
typedef __attribute__((ext_vector_type(8))) unsigned short us8;
typedef __attribute__((ext_vector_type(4))) unsigned short us4;

__device__ __forceinline__ unsigned short f2bf(float f) {
  unsigned u = __float_as_uint(f);
  u += 0x7FFFu + ((u >> 16) & 1u);        // RNE
  return (unsigned short)(u >> 16);
}
__device__ __forceinline__ unsigned cvtpk(float lo, float hi) {
  unsigned r;
  asm("v_cvt_pk_bf16_f32 %0, %1, %2" : "=v"(r) : "v"(lo), "v"(hi));
  return r;
}
__device__ __forceinline__ void gload16(const unsigned short* g, unsigned short* l) {
  __builtin_amdgcn_global_load_lds(
      (const __attribute__((address_space(1))) unsigned int*)g,
      (__attribute__((address_space(3))) unsigned int*)l, 16, 0, 0);
}

// ---------------------------------------------------------------------------
// k_pre: rowsum -> dv; Hb[n][e] = bf16(H[n][e]) (same layout, coalesced);
// xTb[d][n] = bf16(dv*x). Blocks 2500..2503 zero Hb pad rows + xTb pad cols.
// ---------------------------------------------------------------------------
__global__ __launch_bounds__(256) void k_pre(const float* __restrict__ H,
                                             const float* __restrict__ x,
                                             float* __restrict__ dv,
                                             unsigned short* __restrict__ Hb,
                                             unsigned short* __restrict__ xTb) {
  const int t = threadIdx.x, lane = t & 63, w = t >> 6;
  const int b = blockIdx.x;
  if (b >= 2500) {                          // pad maintenance
    const size_t base = (size_t)(20000 + (b - 2500) * 8) * E_;
    for (int i = t; i < 4096; i += 256)     // 8 rows * 4096 shorts = 4096 us8
      *(us8*)&Hb[base + (size_t)i * 8] = (us8){0,0,0,0,0,0,0,0};
    if (b == 2500 && t < 128) {
#pragma unroll
      for (int c = 0; c < 4; ++c)
        *(us8*)&xTb[(size_t)t * XTB_S + 20000 + c * 8] = (us8){0,0,0,0,0,0,0,0};
    }
    return;
  }
  __shared__ float red[32];
  __shared__ float xt[8 * 128];
  const int n0 = b * 8;
  { int r = t >> 5, d4 = (t & 31) * 4;
    *(f32x4*)&xt[r * 128 + d4] = *(const f32x4*)(x + (size_t)(n0 + r) * D_ + d4); }
  float rs[8];
#pragma unroll
  for (int r = 0; r < 8; ++r) {
    rs[r] = 0.f;
    const float* rp = H + (size_t)(n0 + r) * E_;
    unsigned short* hp = Hb + (size_t)(n0 + r) * E_;
#pragma unroll
    for (int j = 0; j < 4; ++j) {
      f32x4 v = *(const f32x4*)(rp + j * 1024 + t * 4);
      rs[r] += (v.x + v.y) + (v.z + v.w);
      union { us4 v4; unsigned u32[2]; } un;
      un.u32[0] = cvtpk(v.x, v.y);
      un.u32[1] = cvtpk(v.z, v.w);
      *(us4*)(hp + j * 1024 + t * 4) = un.v4;
    }
  }
#pragma unroll
  for (int r = 0; r < 8; ++r)
#pragma unroll
    for (int off = 32; off; off >>= 1) rs[r] += __shfl_xor(rs[r], off);
  if (lane == 0) {
#pragma unroll
    for (int r = 0; r < 8; ++r) red[w * 8 + r] = rs[r];
  }
  __syncthreads();
  if (t < 8) {
    float s = red[t] + red[8 + t] + red[16 + t] + red[24 + t];
    float d = s > 0.f ? rsqrtf(s) : 0.f;
    dv[n0 + t] = d;
    red[t] = d;
  }
  __syncthreads();
  if (t < 128) {
    int d = t;
    float v[8];
#pragma unroll
    for (int r = 0; r < 8; ++r) v[r] = xt[r * 128 + d] * red[r];
    union { us8 v8; unsigned u32[4]; } un;
#pragma unroll
    for (int j = 0; j < 4; ++j) un.u32[j] = cvtpk(v[2 * j], v[2 * j + 1]);
    *(us8*)(xTb + (size_t)d * XTB_S + n0) = un.v8;
  }
}

// de[e] = colsum>0 ? 1/colsum : 0  (after gemm1)
__global__ __launch_bounds__(256) void k_fin(const float* __restrict__ desum,
                                             float* __restrict__ de) {
  int e = blockIdx.x * 256 + threadIdx.x;
  float s = desum[e];
  de[e] = s > 0.f ? 1.f / s : 0.f;
}

// Wb = bf16(W), [j][d]
__global__ __launch_bounds__(256) void k_wb(const float* __restrict__ W,
                                            unsigned short* __restrict__ Wb) {
  int tid = blockIdx.x * 256 + threadIdx.x;
  float4 v = *(const float4*)(W + (size_t)tid * 4);
  union { us4 v; unsigned short u[4]; } un;
  un.u[0] = f2bf(v.x); un.u[1] = f2bf(v.y); un.u[2] = f2bf(v.z); un.u[3] = f2bf(v.w);
  *(us4*)(Wb + (size_t)tid * 4) = un.v;
}

// ---------------------------------------------------------------------------
// GEMM1: partialT[s][d][e] = sum_{n chunk s} xdv[n][d] * H[n][e]
// Block tile: 128 d (M) x 64 e (N), BK=64, dbuf, one barrier/step.
// A (xTb) via pre-swizzled gload16; B (Hb) transposed in LDS via u32 loads
// + perm unpack + swizzled b128 writes (bank-structural-minimum).
// Colsum via ones-MFMA on B frags (wy==0 waves). grid = 64 eb * 8 chunks.
// ---------------------------------------------------------------------------
__global__ __launch_bounds__(256) void k_gemm1(const unsigned short* __restrict__ Hb,
                                               const unsigned short* __restrict__ xTb,
                                               float* __restrict__ partialT,
                                               float* __restrict__ desum) {
  __shared__ unsigned short lH[2][64 * 64];   // [e][n] transposed, swizzled
  __shared__ unsigned short lX[2][128 * 64];  // [d][n], swizzled content
  const int t = threadIdx.x, lane = t & 63, w = t >> 6;
  const int eb = blockIdx.x & 63, s = blockIdx.x >> 6;
  const int e0 = eb * 64;
  const int nsteps = 39 + (s == 7);
  const int g0 = s * 39;
  const int lrow = lane >> 3, lslot = lane & 7;
  const int bswz = (lslot ^ lrow) << 3;
  const int wy = w >> 1, wx = w & 1;          // wy: d-half(64), wx: e-half(32)
  // H-transpose stage map: thread handles e-pair (2ep, 2ep+1), n-octet q
  const int ep = t & 31, q = t >> 5;
  const int er0 = 2 * ep, er1 = 2 * ep + 1;
  const int sl0 = (q ^ (er0 & 7)) << 3, sl1 = (q ^ (er1 & 7)) << 3;

  f32x4 acc[4][2];
  f32x4 accC[2];
#pragma unroll
  for (int i = 0; i < 4; ++i)
#pragma unroll
    for (int j = 0; j < 2; ++j) acc[i][j] = (f32x4){0.f, 0.f, 0.f, 0.f};
  accC[0] = (f32x4){0.f, 0.f, 0.f, 0.f};
  accC[1] = (f32x4){0.f, 0.f, 0.f, 0.f};
  bf16x8 ones;
#pragma unroll
  for (int i = 0; i < 8; ++i) ones[i] = (short)0x3F80;

  unsigned hr[8];
  auto LOADH = [&](int g) {
    const unsigned short* p = Hb + (size_t)(g * 64 + q * 8) * E_ + e0 + er0;
#pragma unroll
    for (int j = 0; j < 8; ++j) hr[j] = *(const unsigned*)(p + (size_t)j * E_);
  };
  auto WRITEH = [&](int bufi) {
    union { bf16x8 v; unsigned u[4]; } lo, hi;
#pragma unroll
    for (int p = 0; p < 4; ++p) {
      lo.u[p] = (hr[2 * p] & 0xFFFFu) | (hr[2 * p + 1] << 16);
      hi.u[p] = (hr[2 * p] >> 16) | (hr[2 * p + 1] & 0xFFFF0000u);
    }
    *(bf16x8*)&lH[bufi][er0 * 64 + sl0] = lo.v;
    *(bf16x8*)&lH[bufi][er1 * 64 + sl1] = hi.v;
  };
  auto GLOADX = [&](int g, int bufi) {
#pragma unroll
    for (int i = 0; i < 4; ++i) {
      int c = w * 4 + i;
      gload16(xTb + (size_t)(8 * c + lrow) * XTB_S + g * 64 + bswz,
              &lX[bufi][c * 512]);
    }
  };

  LOADH(g0); GLOADX(g0, 0); WRITEH(0);
  __syncthreads();
  int cur = 0;
  for (int it = 0; it < nsteps; ++it) {
    bool hn = it + 1 < nsteps;
    if (hn) { LOADH(g0 + it + 1); GLOADX(g0 + it + 1, cur ^ 1); }
    const int kg = lane >> 4, fr = lane & 15;
    bf16x8 ax[4][2], bh[2][2];
#pragma unroll
    for (int mi = 0; mi < 4; ++mi) {
      int m = wy * 64 + mi * 16 + fr;
#pragma unroll
      for (int kk = 0; kk < 2; ++kk)
        ax[mi][kk] = *(const bf16x8*)&lX[cur][m * 64 + (((kk * 4 + kg) ^ (m & 7)) << 3)];
    }
#pragma unroll
    for (int ni = 0; ni < 2; ++ni) {
      int n = wx * 32 + ni * 16 + fr;
#pragma unroll
      for (int kk = 0; kk < 2; ++kk)
        bh[ni][kk] = *(const bf16x8*)&lH[cur][n * 64 + (((kk * 4 + kg) ^ (n & 7)) << 3)];
    }
#pragma unroll
    for (int kk = 0; kk < 2; ++kk)
#pragma unroll
      for (int mi = 0; mi < 4; ++mi)
#pragma unroll
        for (int ni = 0; ni < 2; ++ni)
          acc[mi][ni] = __builtin_amdgcn_mfma_f32_16x16x32_bf16(ax[mi][kk], bh[ni][kk], acc[mi][ni], 0, 0, 0);
    if (wy == 0) {
#pragma unroll
      for (int kk = 0; kk < 2; ++kk)
#pragma unroll
        for (int ni = 0; ni < 2; ++ni)
          accC[ni] = __builtin_amdgcn_mfma_f32_16x16x32_bf16(ones, bh[ni][kk], accC[ni], 0, 0, 0);
    }
    if (hn) WRITEH(cur ^ 1);
    __syncthreads();
    cur ^= 1;
  }
  const int kg = lane >> 4, fr = lane & 15;
  if (wy == 0 && kg == 0) {                   // colsum: all D rows equal, take reg 0
#pragma unroll
    for (int ni = 0; ni < 2; ++ni)
      atomicAdd(&desum[e0 + wx * 32 + ni * 16 + fr], accC[ni][0]);
  }
#pragma unroll
  for (int mi = 0; mi < 4; ++mi)
#pragma unroll
    for (int ni = 0; ni < 2; ++ni)
#pragma unroll
      for (int r = 0; r < 4; ++r) {
        int d = wy * 64 + mi * 16 + kg * 4 + r;
        int e = e0 + wx * 32 + ni * 16 + fr;
        partialT[((size_t)s * 128 + d) * E_ + e] = acc[mi][ni][r];
      }
}

// x3T[d][e] = bf16(de[e] * sum_s partialT[s][d][e])
__global__ __launch_bounds__(256) void k_reduce1(const float* __restrict__ partialT,
                                                 const float* __restrict__ de,
                                                 unsigned short* __restrict__ x3T) {
  int tid = blockIdx.x * 256 + threadIdx.x;
  int d = tid >> 12, e = tid & 4095;
  float s = 0.f;
#pragma unroll
  for (int ss = 0; ss < 8; ++ss) s += partialT[((size_t)ss * 128 + d) * E_ + e];
  x3T[(size_t)d * E_ + e] = f2bf(de[e] * s);
}

// ---------------------------------------------------------------------------
// GEMM2: out = (dv*(H @ x3)) @ W^T + b.  64n x 128d block, BK=64, dbuf,
// BOTH operands via pre-swizzled gload16 (Hb rows bf16, x3T rows bf16).
// Epilogue: dv-scale -> bf16 lC (stride 136) -> W MFMA -> +bias.
// ---------------------------------------------------------------------------
__global__ __launch_bounds__(256) void k_gemm2(const unsigned short* __restrict__ Hb,
                                               const unsigned short* __restrict__ x3T,
                                               const unsigned short* __restrict__ Wb,
                                               const float* __restrict__ dv,
                                               const float* __restrict__ bias,
                                               float* __restrict__ out) {
  __shared__ unsigned short sm[2 * 64 * 64 + 2 * 128 * 64];
  __shared__ unsigned short lW[128 * 128];
  unsigned short (*lA)[64 * 64]  = (unsigned short (*)[64 * 64])sm;
  unsigned short (*lB)[128 * 64] = (unsigned short (*)[128 * 64])(sm + 2 * 64 * 64);
  unsigned short* lC = sm;                    // 64*136 shorts, aliases stage bufs
  const int t = threadIdx.x, lane = t & 63, w = t >> 6;
  const int n0b = blockIdx.x * 64;
  const int lrow = lane >> 3, lslot = lane & 7;
  const int bswz = (lslot ^ lrow) << 3;
  const int wy = w >> 1, wx = w & 1;          // wy: n-half(32), wx: d-half(64)

  {                                           // stage W [j][d] once
    int j = t >> 1;
#pragma unroll
    for (int jj = 0; jj < 4; ++jj) {
      int dofs = (t & 1) * 64 + jj * 16;
      const us8* src = (const us8*)(Wb + (size_t)j * 128 + dofs);
      *(us8*)&lW[j * 128 + dofs]     = src[0];
      *(us8*)&lW[j * 128 + dofs + 8] = src[1];
    }
  }

  auto GLOADA = [&](int g, int bufi) {
#pragma unroll
    for (int i = 0; i < 2; ++i) {
      int c = w * 2 + i;
      gload16(Hb + (size_t)(n0b + 8 * c + lrow) * E_ + g * 64 + bswz,
              &lA[bufi][c * 512]);
    }
  };
  auto GLOADB = [&](int g, int bufi) {
#pragma unroll
    for (int i = 0; i < 4; ++i) {
      int c = w * 4 + i;
      gload16(x3T + (size_t)(8 * c + lrow) * E_ + g * 64 + bswz,
              &lB[bufi][c * 512]);
    }
  };

  f32x4 acc[2][4];
#pragma unroll
  for (int i = 0; i < 2; ++i)
#pragma unroll
    for (int j = 0; j < 4; ++j) acc[i][j] = (f32x4){0.f, 0.f, 0.f, 0.f};

  GLOADA(0, 0); GLOADB(0, 0);
  __syncthreads();
  int cur = 0;
  for (int it = 0; it < 64; ++it) {
    bool hn = it < 63;
    if (hn) { GLOADA(it + 1, cur ^ 1); GLOADB(it + 1, cur ^ 1); }
    const int kg = lane >> 4, fr = lane & 15;
    bf16x8 af[2][2], bfr[4][2];
#pragma unroll
    for (int mi = 0; mi < 2; ++mi) {
      int m = wy * 32 + mi * 16 + fr;
#pragma unroll
      for (int kk = 0; kk < 2; ++kk)
        af[mi][kk] = *(const bf16x8*)&lA[cur][m * 64 + (((kk * 4 + kg) ^ (m & 7)) << 3)];
    }
#pragma unroll
    for (int ni = 0; ni < 4; ++ni) {
      int d = wx * 64 + ni * 16 + fr;
#pragma unroll
      for (int kk = 0; kk < 2; ++kk)
        bfr[ni][kk] = *(const bf16x8*)&lB[cur][d * 64 + (((kk * 4 + kg) ^ (d & 7)) << 3)];
    }
#pragma unroll
    for (int kk = 0; kk < 2; ++kk)
#pragma unroll
      for (int mi = 0; mi < 2; ++mi)
#pragma unroll
        for (int ni = 0; ni < 4; ++ni)
          acc[mi][ni] = __builtin_amdgcn_mfma_f32_16x16x32_bf16(af[mi][kk], bfr[ni][kk], acc[mi][ni], 0, 0, 0);
    __syncthreads();
    cur ^= 1;
  }
  // epilogue: dv-scale -> bf16 -> lC (stride 136)
#pragma unroll
  for (int mi = 0; mi < 2; ++mi) {
    float dvv[4];
#pragma unroll
    for (int r = 0; r < 4; ++r)
      dvv[r] = dv[min(n0b + wy * 32 + mi * 16 + (lane >> 4) * 4 + r, N_ - 1)];
#pragma unroll
    for (int ni = 0; ni < 4; ++ni)
#pragma unroll
      for (int r = 0; r < 4; ++r) {
        int row = wy * 32 + mi * 16 + (lane >> 4) * 4 + r;
        int col = wx * 64 + ni * 16 + (lane & 15);
        lC[row * 136 + col] = f2bf(acc[mi][ni][r] * dvv[r]);
      }
  }
  __syncthreads();
  f32x4 acc2[2][4];
#pragma unroll
  for (int i = 0; i < 2; ++i)
#pragma unroll
    for (int j = 0; j < 4; ++j) acc2[i][j] = (f32x4){0.f, 0.f, 0.f, 0.f};
#pragma unroll
  for (int ks = 0; ks < 4; ++ks) {
    int kofs = ks * 32 + (lane >> 4) * 8;
    bf16x8 a2[2], b2[4];
#pragma unroll
    for (int mi = 0; mi < 2; ++mi) {
      int m = wy * 32 + mi * 16 + (lane & 15);
      a2[mi] = *(const bf16x8*)&lC[m * 136 + kofs];
    }
#pragma unroll
    for (int ni = 0; ni < 4; ++ni) {
      int j = wx * 64 + ni * 16 + (lane & 15);
      b2[ni] = *(const bf16x8*)&lW[j * 128 + kofs];
    }
#pragma unroll
    for (int mi = 0; mi < 2; ++mi)
#pragma unroll
      for (int ni = 0; ni < 4; ++ni)
        acc2[mi][ni] = __builtin_amdgcn_mfma_f32_16x16x32_bf16(a2[mi], b2[ni], acc2[mi][ni], 0, 0, 0);
  }
#pragma unroll
  for (int mi = 0; mi < 2; ++mi)
#pragma unroll
    for (int ni = 0; ni < 4; ++ni) {
      int j = wx * 64 + ni * 16 + (lane & 15);
      float bb = bias[j];
#pragma unroll
      for (int r = 0; r < 4; ++r) {
        int n = n0b + wy * 32 + mi * 16 + (lane >> 4) * 4 + r;
        if (n < N_) out[(size_t)n * D_ + j] = acc2[mi][ni][r] + bb;
      }
    }
}

// ---------------------------------------------------------------------------
extern "C" void kernel_launch(void* const* d_in, const int* in_sizes, int n_in,
                              void* d_out, int out_size, void* d_ws, size_t ws_size,
                              hipStream_t stream) {
  const float* x = (const float*)d_in[0];
  const float* H = (const float*)d_in[1];
  const float* W = (const float*)d_in[2];
  const float* b = (const float*)d_in[3];
  float* out = (float*)d_out;
  char* ws = (char*)d_ws;
  float*          desum    = (float*)(ws);                     // 16 KB
  float*          de       = (float*)(ws + 16384);             // 16 KB
  float*          dv       = (float*)(ws + 32768);             // 80 KB pad
  unsigned short* Wb       = (unsigned short*)(ws + 112896);   // 32 KB
  unsigned short* xTb      = (unsigned short*)(ws + 145664);   // 128*20032*2 = 5,128,192
  unsigned short* x3T      = (unsigned short*)(ws + 5273856);  // 1,048,576
  float*          partialT = (float*)(ws + 6322432);           // 16,777,216
  unsigned short* Hb       = (unsigned short*)(ws + 23099648); // 20032*4096*2 = 164,102,144

  hipMemsetAsync(desum, 0, 16384, stream);
  k_pre<<<2504, 256, 0, stream>>>(H, x, dv, Hb, xTb);
  k_wb<<<16, 256, 0, stream>>>(W, Wb);
  k_gemm1<<<512, 256, 0, stream>>>(Hb, xTb, partialT, desum);
  k_fin<<<16, 256, 0, stream>>>(desum, de);
  k_reduce1<<<2048, 256, 0, stream>>>(partialT, de, x3T);
  k_gemm2<<<313, 256, 0, stream>>>(Hb, x3T, Wb, dv, b, out);
}